// Round 1
// baseline (1622.099 us; speedup 1.0000x reference)
//
#include <hip/hip_runtime.h>
#include <hip/hip_bf16.h>
#include <stdint.h>

#define IGNORE_INDEX (-100)

typedef __attribute__((ext_vector_type(8))) short bf16x8;
typedef __attribute__((ext_vector_type(4))) float f32x4;

static constexpr int Bv = 4, Sv = 2048, Dv = 2048, Vv = 32000;
static constexpr int Nv = Bv * (Sv - 1);   // 8188 valid rows
static constexpr int NP = 8192;            // padded row count
static constexpr int TILE = 128;
static constexpr int BK = 64;

typedef const __attribute__((address_space(1))) unsigned int* gptr_t;
typedef __attribute__((address_space(3))) unsigned int* lptr_t;

__device__ __forceinline__ unsigned short f2bf(float f) {
    unsigned int u = __float_as_uint(f);
    u += 0x7fffu + ((u >> 16) & 1u);   // round-to-nearest-even
    return (unsigned short)(u >> 16);
}

// ---- fp32 -> bf16 for lm_head_weight [V, D] -------------------------------
__global__ void convert_w_kernel(const float* __restrict__ w,
                                 unsigned short* __restrict__ wbf) {
    int i = blockIdx.x * blockDim.x + threadIdx.x;   // one float4
    const float4 v = ((const float4*)w)[i];
    ushort4 o;
    o.x = f2bf(v.x); o.y = f2bf(v.y); o.z = f2bf(v.z); o.w = f2bf(v.w);
    ((ushort4*)wbf)[i] = o;
}

// ---- fp32 -> bf16 for shifted hidden states, rows padded to 8192 ----------
__global__ void convert_h_kernel(const float* __restrict__ h,
                                 unsigned short* __restrict__ hbf) {
    int i = blockIdx.x * blockDim.x + threadIdx.x;   // one float4
    int e0 = i * 4;
    int n = e0 >> 11;       // / 2048
    int d = e0 & 2047;
    ushort4 o;
    if (n < Nv) {
        int b = n / 2047;            // batch
        int s = n - b * 2047;        // position 0..2046
        const float4 v = *(const float4*)(h + ((size_t)b * Sv + s) * Dv + d);
        o.x = f2bf(v.x); o.y = f2bf(v.y); o.z = f2bf(v.z); o.w = f2bf(v.w);
    } else {
        o.x = 0; o.y = 0; o.z = 0; o.w = 0;
    }
    ((ushort4*)hbf)[i] = o;
}

// ---- shifted labels + zero-init of accumulators ---------------------------
__global__ void prep_meta_kernel(const int* __restrict__ labels,
                                 int* __restrict__ t,
                                 float* __restrict__ sumexp,
                                 float* __restrict__ gold) {
    int n = blockIdx.x * blockDim.x + threadIdx.x;
    if (n >= NP) return;
    sumexp[n] = 0.0f;
    gold[n] = 0.0f;
    int tv = IGNORE_INDEX;
    if (n < Nv) {
        int b = n / 2047;
        int s = n - b * 2047;
        tv = labels[b * Sv + s + 1];   // causal shift
    }
    t[n] = tv;
}

// ---- fused GEMM + exp-reduce + gold gather --------------------------------
// grid: (NP/128, V/128); block: 256 (4 waves, each a 64x64 quadrant)
__global__ __launch_bounds__(256, 2)
void ce_gemm(const unsigned short* __restrict__ hbf,
             const unsigned short* __restrict__ wbf,
             const int* __restrict__ t,
             float* __restrict__ sumexp,
             float* __restrict__ gold) {
    __shared__ unsigned short lds_a[TILE * BK];
    __shared__ unsigned short lds_b[TILE * BK];
    __shared__ float lds_rowsum[TILE];
    __shared__ int lds_t[TILE];

    const int tid  = threadIdx.x;
    const int lane = tid & 63;
    const int wave = tid >> 6;
    const int r    = wave >> 1;     // row half of the 128x128 tile
    const int c    = wave & 1;      // col half
    const int quad = lane >> 4;
    const int l15  = lane & 15;
    const int R0   = blockIdx.x * TILE;
    const int C0   = blockIdx.y * TILE;

    f32x4 acc[4][4];
    const f32x4 z = {0.f, 0.f, 0.f, 0.f};
#pragma unroll
    for (int mi = 0; mi < 4; ++mi)
#pragma unroll
        for (int ni = 0; ni < 4; ++ni)
            acc[mi][ni] = z;

    // staging: each thread loads one 16B chunk per iteration, 4 iterations
    const int ld_r = tid >> 3;          // 0..31 (8 threads per 64-elem row)
    const int ld_c = (tid & 7) * 8;     // element col within K-tile
    const unsigned short* ga = hbf + (size_t)(R0 + ld_r) * Dv + ld_c;
    const unsigned short* gb = wbf + (size_t)(C0 + ld_r) * Dv + ld_c;
    unsigned short* la = lds_a + tid * 8;
    unsigned short* lb = lds_b + tid * 8;

    for (int k0 = 0; k0 < Dv; k0 += BK) {
        __syncthreads();   // previous tile fully consumed
#pragma unroll
        for (int i = 0; i < 4; ++i) {
            __builtin_amdgcn_global_load_lds(
                (gptr_t)(ga + (size_t)i * 32 * Dv + k0),
                (lptr_t)(la + i * 2048), 16, 0, 0);
            __builtin_amdgcn_global_load_lds(
                (gptr_t)(gb + (size_t)i * 32 * Dv + k0),
                (lptr_t)(lb + i * 2048), 16, 0, 0);
        }
        __syncthreads();   // drains vmcnt before LDS reads
#pragma unroll
        for (int ks = 0; ks < BK; ks += 32) {
            bf16x8 af[4], bfr[4];
#pragma unroll
            for (int mi = 0; mi < 4; ++mi)
                af[mi] = *(const bf16x8*)(lds_a + (r * 64 + mi * 16 + l15) * BK + ks + quad * 8);
#pragma unroll
            for (int ni = 0; ni < 4; ++ni)
                bfr[ni] = *(const bf16x8*)(lds_b + (c * 64 + ni * 16 + l15) * BK + ks + quad * 8);
#pragma unroll
            for (int mi = 0; mi < 4; ++mi)
#pragma unroll
                for (int ni = 0; ni < 4; ++ni)
                    acc[mi][ni] = __builtin_amdgcn_mfma_f32_16x16x32_bf16(
                        af[mi], bfr[ni], acc[mi][ni], 0, 0, 0);
        }
    }

    // ---- fused epilogue: exp + row-sum + gold capture ----
    __syncthreads();
    if (tid < TILE) {
        lds_rowsum[tid] = 0.0f;
        lds_t[tid] = t[R0 + tid];
    }
    __syncthreads();

#pragma unroll
    for (int mi = 0; mi < 4; ++mi) {
#pragma unroll
        for (int reg = 0; reg < 4; ++reg) {
            const int lrow = r * 64 + mi * 16 + quad * 4 + reg;  // C/D: row = quad*4+reg
            const int grow = R0 + lrow;
            const int lbl  = lds_t[lrow];
            float s = 0.0f;
#pragma unroll
            for (int ni = 0; ni < 4; ++ni) {
                const float v = acc[mi][ni][reg];
                s += __expf(v);
                const int gcol = C0 + c * 64 + ni * 16 + l15;    // C/D: col = lane&15
                if (lbl == gcol) gold[grow] = v;                  // unique writer
            }
            // reduce across the 16 column-lanes sharing this row
#pragma unroll
            for (int off = 1; off < 16; off <<= 1)
                s += __shfl_xor(s, off, 64);
            if (l15 == 0) atomicAdd(&lds_rowsum[lrow], s);
        }
    }
    __syncthreads();
    if (tid < TILE) {
        const int grow = R0 + tid;
        if (grow < Nv) atomicAdd(&sumexp[grow], lds_rowsum[tid]);
    }
}

// ---- final scalar: mean over valid rows of log(sumexp) - gold -------------
__global__ void ce_finalize(const float* __restrict__ sumexp,
                            const float* __restrict__ gold,
                            const int* __restrict__ t,
                            float* __restrict__ out) {
    __shared__ float ssum[4];
    __shared__ float scnt[4];
    float s = 0.0f, cnt = 0.0f;
    for (int n = threadIdx.x; n < Nv; n += 256) {
        if (t[n] != IGNORE_INDEX) {
            s += logf(sumexp[n]) - gold[n];
            cnt += 1.0f;
        }
    }
#pragma unroll
    for (int off = 32; off > 0; off >>= 1) {
        s += __shfl_down(s, off, 64);
        cnt += __shfl_down(cnt, off, 64);
    }
    const int wid = threadIdx.x >> 6;
    if ((threadIdx.x & 63) == 0) { ssum[wid] = s; scnt[wid] = cnt; }
    __syncthreads();
    if (threadIdx.x == 0) {
        float S = 0.0f, C = 0.0f;
        for (int i = 0; i < 4; ++i) { S += ssum[i]; C += scnt[i]; }
        out[0] = S / fmaxf(C, 1.0f);
    }
}

extern "C" void kernel_launch(void* const* d_in, const int* in_sizes, int n_in,
                              void* d_out, int out_size, void* d_ws, size_t ws_size,
                              hipStream_t stream) {
    const float* h      = (const float*)d_in[0];   // [4, 2048, 2048] fp32
    const float* w      = (const float*)d_in[1];   // [32000, 2048] fp32
    const int*   labels = (const int*)d_in[2];     // [4, 2048] int
    float* out = (float*)d_out;

    char* ws = (char*)d_ws;
    unsigned short* hbf = (unsigned short*)ws;                                   // 33.6 MB
    unsigned short* wbf = (unsigned short*)(ws + (size_t)NP * Dv * 2);           // 131 MB
    char* tail = ws + (size_t)NP * Dv * 2 + (size_t)Vv * Dv * 2;
    float* sumexp = (float*)tail;
    float* gold   = (float*)(tail + (size_t)NP * 4);
    int*   t      = (int*)(tail + (size_t)NP * 8);

    hipLaunchKernelGGL(convert_w_kernel, dim3((Vv * Dv / 4) / 256), dim3(256), 0, stream, w, wbf);
    hipLaunchKernelGGL(convert_h_kernel, dim3((NP * Dv / 4) / 256), dim3(256), 0, stream, h, hbf);
    hipLaunchKernelGGL(prep_meta_kernel, dim3(NP / 256), dim3(256), 0, stream, labels, t, sumexp, gold);
    hipLaunchKernelGGL(ce_gemm, dim3(NP / TILE, Vv / TILE), dim3(256), 0, stream,
                       hbf, wbf, t, sumexp, gold);
    hipLaunchKernelGGL(ce_finalize, dim3(1), dim3(256), 0, stream, sumexp, gold, t, out);
}

// Round 2
// 1360.936 us; speedup vs baseline: 1.1919x; 1.1919x over previous
//
#include <hip/hip_runtime.h>
#include <hip/hip_bf16.h>
#include <stdint.h>

#define IGNORE_INDEX (-100)

typedef __attribute__((ext_vector_type(8))) short bf16x8;
typedef __attribute__((ext_vector_type(4))) float f32x4;

static constexpr int Bv = 4, Sv = 2048, Dv = 2048, Vv = 32000;
static constexpr int Nv = Bv * (Sv - 1);   // 8188 valid rows
static constexpr int NP = 8192;            // padded row count
static constexpr int TILE = 128;
static constexpr int BK = 64;

typedef const __attribute__((address_space(1))) unsigned int* gptr_t;
typedef __attribute__((address_space(3))) unsigned int* lptr_t;

__device__ __forceinline__ unsigned short f2bf(float f) {
    unsigned int u = __float_as_uint(f);
    u += 0x7fffu + ((u >> 16) & 1u);   // round-to-nearest-even
    return (unsigned short)(u >> 16);
}

// ---- fp32 -> bf16 for lm_head_weight [V, D] -------------------------------
__global__ void convert_w_kernel(const float* __restrict__ w,
                                 unsigned short* __restrict__ wbf) {
    int i = blockIdx.x * blockDim.x + threadIdx.x;   // one float4
    const float4 v = ((const float4*)w)[i];
    ushort4 o;
    o.x = f2bf(v.x); o.y = f2bf(v.y); o.z = f2bf(v.z); o.w = f2bf(v.w);
    ((ushort4*)wbf)[i] = o;
}

// ---- fp32 -> bf16 for shifted hidden states, rows padded to 8192 ----------
__global__ void convert_h_kernel(const float* __restrict__ h,
                                 unsigned short* __restrict__ hbf) {
    int i = blockIdx.x * blockDim.x + threadIdx.x;   // one float4
    int e0 = i * 4;
    int n = e0 >> 11;       // / 2048
    int d = e0 & 2047;
    ushort4 o;
    if (n < Nv) {
        int b = n / 2047;            // batch
        int s = n - b * 2047;        // position 0..2046
        const float4 v = *(const float4*)(h + ((size_t)b * Sv + s) * Dv + d);
        o.x = f2bf(v.x); o.y = f2bf(v.y); o.z = f2bf(v.z); o.w = f2bf(v.w);
    } else {
        o.x = 0; o.y = 0; o.z = 0; o.w = 0;
    }
    ((ushort4*)hbf)[i] = o;
}

// ---- shifted labels + zero-init of accumulators ---------------------------
__global__ void prep_meta_kernel(const int* __restrict__ labels,
                                 int* __restrict__ t,
                                 float* __restrict__ sumexp,
                                 float* __restrict__ gold) {
    int n = blockIdx.x * blockDim.x + threadIdx.x;
    if (n >= NP) return;
    sumexp[n] = 0.0f;
    gold[n] = 0.0f;
    int tv = IGNORE_INDEX;
    if (n < Nv) {
        int b = n / 2047;
        int s = n - b * 2047;
        tv = labels[b * Sv + s + 1];   // causal shift
    }
    t[n] = tv;
}

// ---- fused GEMM + exp-reduce + gold gather --------------------------------
// grid: (NP/128, V/128); block: 256 (4 waves, each a 64x64 quadrant)
// LDS layout XOR-swizzled: physical chunk = logical chunk ^ (row & 7);
// swizzle realized on the PRODUCER side (global src permutation) because
// global_load_lds dest is hardwired to wave-base + lane*16.
__global__ __launch_bounds__(256, 2)
void ce_gemm(const unsigned short* __restrict__ hbf,
             const unsigned short* __restrict__ wbf,
             const int* __restrict__ t,
             float* __restrict__ sumexp,
             float* __restrict__ gold) {
    __shared__ unsigned short lds_a[TILE * BK];
    __shared__ unsigned short lds_b[TILE * BK];
    __shared__ float lds_rowsum[TILE];
    __shared__ int lds_t[TILE];

    const int tid  = threadIdx.x;
    const int lane = tid & 63;
    const int wave = tid >> 6;
    const int r    = wave >> 1;     // row half of the 128x128 tile
    const int c    = wave & 1;      // col half
    const int quad = lane >> 4;
    const int l15  = lane & 15;
    const int R0   = blockIdx.x * TILE;
    const int C0   = blockIdx.y * TILE;

    f32x4 acc[4][4];
    const f32x4 z = {0.f, 0.f, 0.f, 0.f};
#pragma unroll
    for (int mi = 0; mi < 4; ++mi)
#pragma unroll
        for (int ni = 0; ni < 4; ++ni)
            acc[mi][ni] = z;

    // staging: thread tid owns LDS slot (row = tid>>3, chunk jl = tid&7);
    // it fetches global chunk jg = jl ^ (row & 7)  -> swizzled LDS layout
    const int ld_r = tid >> 3;                       // 0..31
    const int jg   = (tid & 7) ^ (ld_r & 7);
    const int ld_c = jg * 8;                         // element col within K-tile
    const unsigned short* ga = hbf + (size_t)(R0 + ld_r) * Dv + ld_c;
    const unsigned short* gb = wbf + (size_t)(C0 + ld_r) * Dv + ld_c;
    unsigned short* la = lds_a + tid * 8;
    unsigned short* lb = lds_b + tid * 8;

    for (int k0 = 0; k0 < Dv; k0 += BK) {
        __syncthreads();   // previous tile fully consumed
#pragma unroll
        for (int i = 0; i < 4; ++i) {
            // row advances by 32 each i: (row&7) unchanged, swizzle still valid
            __builtin_amdgcn_global_load_lds(
                (gptr_t)(ga + (size_t)i * 32 * Dv + k0),
                (lptr_t)(la + i * 2048), 16, 0, 0);
            __builtin_amdgcn_global_load_lds(
                (gptr_t)(gb + (size_t)i * 32 * Dv + k0),
                (lptr_t)(lb + i * 2048), 16, 0, 0);
        }
        __syncthreads();   // drains vmcnt before LDS reads
#pragma unroll
        for (int ks = 0; ks < BK; ks += 32) {
            bf16x8 af[4], bfr[4];
            const int cbase = quad + (ks >> 3);     // logical 16B-chunk index
#pragma unroll
            for (int mi = 0; mi < 4; ++mi) {
                const int arow = r * 64 + mi * 16 + l15;
                af[mi] = *(const bf16x8*)(lds_a + arow * BK + ((cbase ^ (arow & 7)) * 8));
            }
#pragma unroll
            for (int ni = 0; ni < 4; ++ni) {
                const int brow = c * 64 + ni * 16 + l15;
                bfr[ni] = *(const bf16x8*)(lds_b + brow * BK + ((cbase ^ (brow & 7)) * 8));
            }
#pragma unroll
            for (int mi = 0; mi < 4; ++mi)
#pragma unroll
                for (int ni = 0; ni < 4; ++ni)
                    acc[mi][ni] = __builtin_amdgcn_mfma_f32_16x16x32_bf16(
                        af[mi], bfr[ni], acc[mi][ni], 0, 0, 0);
        }
    }

    // ---- fused epilogue: exp + row-sum + gold capture ----
    __syncthreads();
    if (tid < TILE) {
        lds_rowsum[tid] = 0.0f;
        lds_t[tid] = t[R0 + tid];
    }
    __syncthreads();

#pragma unroll
    for (int mi = 0; mi < 4; ++mi) {
#pragma unroll
        for (int reg = 0; reg < 4; ++reg) {
            const int lrow = r * 64 + mi * 16 + quad * 4 + reg;  // C/D: row = quad*4+reg
            const int grow = R0 + lrow;
            const int lbl  = lds_t[lrow];
            float s = 0.0f;
#pragma unroll
            for (int ni = 0; ni < 4; ++ni) {
                const float v = acc[mi][ni][reg];
                s += __expf(v);
                const int gcol = C0 + c * 64 + ni * 16 + l15;    // C/D: col = lane&15
                if (lbl == gcol) gold[grow] = v;                  // unique writer
            }
            // reduce across the 16 column-lanes sharing this row
#pragma unroll
            for (int off = 1; off < 16; off <<= 1)
                s += __shfl_xor(s, off, 64);
            if (l15 == 0) atomicAdd(&lds_rowsum[lrow], s);
        }
    }
    __syncthreads();
    if (tid < TILE) {
        const int grow = R0 + tid;
        if (grow < Nv) atomicAdd(&sumexp[grow], lds_rowsum[tid]);
    }
}

// ---- final scalar: mean over valid rows of log(sumexp) - gold -------------
__global__ void ce_finalize(const float* __restrict__ sumexp,
                            const float* __restrict__ gold,
                            const int* __restrict__ t,
                            float* __restrict__ out) {
    __shared__ float ssum[4];
    __shared__ float scnt[4];
    float s = 0.0f, cnt = 0.0f;
    for (int n = threadIdx.x; n < Nv; n += 256) {
        if (t[n] != IGNORE_INDEX) {
            s += logf(sumexp[n]) - gold[n];
            cnt += 1.0f;
        }
    }
#pragma unroll
    for (int off = 32; off > 0; off >>= 1) {
        s += __shfl_down(s, off, 64);
        cnt += __shfl_down(cnt, off, 64);
    }
    const int wid = threadIdx.x >> 6;
    if ((threadIdx.x & 63) == 0) { ssum[wid] = s; scnt[wid] = cnt; }
    __syncthreads();
    if (threadIdx.x == 0) {
        float S = 0.0f, C = 0.0f;
        for (int i = 0; i < 4; ++i) { S += ssum[i]; C += scnt[i]; }
        out[0] = S / fmaxf(C, 1.0f);
    }
}

extern "C" void kernel_launch(void* const* d_in, const int* in_sizes, int n_in,
                              void* d_out, int out_size, void* d_ws, size_t ws_size,
                              hipStream_t stream) {
    const float* h      = (const float*)d_in[0];   // [4, 2048, 2048] fp32
    const float* w      = (const float*)d_in[1];   // [32000, 2048] fp32
    const int*   labels = (const int*)d_in[2];     // [4, 2048] int
    float* out = (float*)d_out;

    char* ws = (char*)d_ws;
    unsigned short* hbf = (unsigned short*)ws;                                   // 33.6 MB
    unsigned short* wbf = (unsigned short*)(ws + (size_t)NP * Dv * 2);           // 131 MB
    char* tail = ws + (size_t)NP * Dv * 2 + (size_t)Vv * Dv * 2;
    float* sumexp = (float*)tail;
    float* gold   = (float*)(tail + (size_t)NP * 4);
    int*   t      = (int*)(tail + (size_t)NP * 8);

    hipLaunchKernelGGL(convert_w_kernel, dim3((Vv * Dv / 4) / 256), dim3(256), 0, stream, w, wbf);
    hipLaunchKernelGGL(convert_h_kernel, dim3((NP * Dv / 4) / 256), dim3(256), 0, stream, h, hbf);
    hipLaunchKernelGGL(prep_meta_kernel, dim3(NP / 256), dim3(256), 0, stream, labels, t, sumexp, gold);
    hipLaunchKernelGGL(ce_gemm, dim3(NP / TILE, Vv / TILE), dim3(256), 0, stream,
                       hbf, wbf, t, sumexp, gold);
    hipLaunchKernelGGL(ce_finalize, dim3(1), dim3(256), 0, stream, sumexp, gold, t, out);
}